// Round 1
// baseline (14423.219 us; speedup 1.0000x reference)
//
#include <hip/hip_runtime.h>

#define NU 100000
#define NI 50000
#define NN 150000
#define DD 64
#define KK 32
#define EUI 1000000
#define EUU 500000
#define EII 500000

static inline int cdiv(long a, int b) { return (int)((a + b - 1) / b); }

// ---------------- precompute kernels ----------------

__global__ void k_deg(const int* __restrict__ u, const int* __restrict__ i,
                      float* __restrict__ deg) {
    int e = blockIdx.x * blockDim.x + threadIdx.x;
    if (e < EUI) {
        atomicAdd(&deg[u[e]], 1.0f);
        atomicAdd(&deg[NU + i[e]], 1.0f);
    }
}

__global__ void k_dinv(float* __restrict__ d, int n) {
    int t = blockIdx.x * blockDim.x + threadIdx.x;
    if (t < n) { float v = d[t]; d[t] = v > 0.0f ? rsqrtf(v) : 0.0f; }
}

__global__ void k_rowsum(const int* __restrict__ h, const float* __restrict__ w,
                         float* __restrict__ rs, int E) {
    int e = blockIdx.x * blockDim.x + threadIdx.x;
    if (e < E) atomicAdd(&rs[h[e]], w[e]);
}

__global__ void k_invert(float* __restrict__ s, int n) {
    int t = blockIdx.x * blockDim.x + threadIdx.x;
    if (t < n) { float v = s[t]; s[t] = (v != 0.0f) ? 1.0f / v : 0.0f; }
}

// ---------------- spmm kernels (edge-parallel, atomics) ----------------

__global__ void k_spmm_ui_sym(const int* __restrict__ eu, const int* __restrict__ ei,
                              const float* __restrict__ dinv, const float* __restrict__ x,
                              float* __restrict__ out) {
    int gid = blockIdx.x * blockDim.x + threadIdx.x;
    int e = gid >> 6, f = gid & 63;
    if (e >= EUI) return;
    int un = eu[e], in = NU + ei[e];
    float val = dinv[un] * dinv[in];
    atomicAdd(&out[un * DD + f], val * x[in * DD + f]);
    atomicAdd(&out[in * DD + f], val * x[un * DD + f]);
}

// out[h[e]] += w[e]*inv_rs[h[e]] * x[t[e]]
__global__ void k_spmm_w(const int* __restrict__ h, const int* __restrict__ t,
                         const float* __restrict__ w, const float* __restrict__ inv_rs,
                         const float* __restrict__ x, float* __restrict__ out, int E) {
    int gid = blockIdx.x * blockDim.x + threadIdx.x;
    int e = gid >> 6, f = gid & 63;
    if (e >= E) return;
    int hh = h[e], tt = t[e];
    float val = w[e] * inv_rs[hh];
    atomicAdd(&out[hh * DD + f], val * x[tt * DD + f]);
}

__global__ void k_spmm_ui_t1(const int* __restrict__ eu, const int* __restrict__ ei,
                             const float* __restrict__ wu, const float* __restrict__ wi,
                             const float* __restrict__ iru, const float* __restrict__ iri,
                             const float* __restrict__ x, float* __restrict__ out) {
    int gid = blockIdx.x * blockDim.x + threadIdx.x;
    int e = gid >> 6, f = gid & 63;
    if (e >= EUI) return;
    int un = eu[e], ii = ei[e], in = NU + ii;
    float vu = wu[e] * iru[un];
    float vi = wi[e] * iri[ii];
    atomicAdd(&out[un * DD + f], vu * x[in * DD + f]);
    atomicAdd(&out[in * DD + f], vi * x[un * DD + f]);
}

// ---------------- intent kernels ----------------

__device__ __forceinline__ void intent_dist(const float* __restrict__ hrow,
                                            const float* __restrict__ trow,
                                            const float* __restrict__ Wl,
                                            float* dist, float* alpha_out) {
    float logit[KK];
#pragma unroll
    for (int k = 0; k < KK; k++) logit[k] = 0.0f;
    float dot = 0.0f;
    const float4* hp = (const float4*)hrow;
    const float4* tp = (const float4*)trow;
#pragma unroll 4
    for (int l4 = 0; l4 < 16; l4++) {
        float4 h4 = hp[l4], t4 = tp[l4];
        float p0 = h4.x * t4.x, p1 = h4.y * t4.y, p2 = h4.z * t4.z, p3 = h4.w * t4.w;
        dot += p0 + p1 + p2 + p3;
        const float* w = &Wl[l4 * 4 * KK];
#pragma unroll
        for (int k = 0; k < KK; k++)
            logit[k] += p0 * w[k] + p1 * w[KK + k] + p2 * w[2 * KK + k] + p3 * w[3 * KK + k];
    }
    float m = logit[0];
#pragma unroll
    for (int k = 1; k < KK; k++) m = fmaxf(m, logit[k]);
    float s = 0.0f;
#pragma unroll
    for (int k = 0; k < KK; k++) { float ev = __expf(logit[k] - m); dist[k] = ev; s += ev; }
    float invs = 1.0f / s;
#pragma unroll
    for (int k = 0; k < KK; k++) dist[k] *= invs;
    *alpha_out = 0.5f * (dot + 1.0f);
}

// pass A: agg[head] += alpha*dist
template <bool DUAL>
__global__ void k_intent_a(const int* __restrict__ eh, const int* __restrict__ et, int toff,
                           const float* __restrict__ feat, const float* __restrict__ intents,
                           float* __restrict__ agg_a, float* __restrict__ agg_b, int E) {
    __shared__ float Wl[DD * KK];
    for (int idx = threadIdx.x; idx < DD * KK; idx += blockDim.x) Wl[idx] = intents[idx];
    __syncthreads();
    int e = blockIdx.x * blockDim.x + threadIdx.x;
    if (e >= E) return;
    int hn = eh[e], tnr = et[e];
    float dist[KK]; float alpha;
    intent_dist(feat + (size_t)hn * DD, feat + (size_t)(tnr + toff) * DD, Wl, dist, &alpha);
    float* pa = agg_a + (size_t)hn * KK;
#pragma unroll
    for (int k = 0; k < KK; k++) {
        float v = alpha * dist[k];
        atomicAdd(&pa[k], v);
        if (DUAL) atomicAdd(&agg_b[(size_t)tnr * KK + k], v);
    }
}

// pass C: recompute dist; w[e] = alpha*(1/K)*sum_k dist*recip[head]; rowsum of w
template <bool DUAL>
__global__ void k_intent_c(const int* __restrict__ eh, const int* __restrict__ et, int toff,
                           const float* __restrict__ feat, const float* __restrict__ intents,
                           const float* __restrict__ recip_a, const float* __restrict__ recip_b,
                           float* __restrict__ w_a, float* __restrict__ w_b,
                           float* __restrict__ rs_a, float* __restrict__ rs_b, int E) {
    __shared__ float Wl[DD * KK];
    for (int idx = threadIdx.x; idx < DD * KK; idx += blockDim.x) Wl[idx] = intents[idx];
    __syncthreads();
    int e = blockIdx.x * blockDim.x + threadIdx.x;
    if (e >= E) return;
    int hn = eh[e], tnr = et[e];
    float dist[KK]; float alpha;
    intent_dist(feat + (size_t)hn * DD, feat + (size_t)(tnr + toff) * DD, Wl, dist, &alpha);
    const float* ra = recip_a + (size_t)hn * KK;
    float sa = 0.0f;
#pragma unroll
    for (int k = 0; k < KK; k++) sa += dist[k] * ra[k];
    float wa = alpha * sa * (1.0f / KK);
    w_a[e] = wa;
    atomicAdd(&rs_a[hn], wa);
    if (DUAL) {
        const float* rb = recip_b + (size_t)tnr * KK;
        float sb = 0.0f;
#pragma unroll
        for (int k = 0; k < KK; k++) sb += dist[k] * rb[k];
        float wb = alpha * sb * (1.0f / KK);
        w_b[e] = wb;
        atomicAdd(&rs_b[tnr], wb);
    }
}

// ---------------- dense kernels ----------------

// z (+)= y @ W2blk (+ b2 on INIT). W2blk is 64x64 row-major [l][c].
template <bool INIT>
__global__ void k_gate_gemm(const float* __restrict__ y, const float* __restrict__ W2blk,
                            const float* __restrict__ b2, float* __restrict__ z, int nrows) {
    __shared__ float Wl[DD * DD];
    __shared__ float Yl[4][DD];
    for (int idx = threadIdx.x; idx < DD * DD; idx += blockDim.x) Wl[idx] = W2blk[idx];
    int r = threadIdx.x >> 6, c = threadIdx.x & 63;
    int row = blockIdx.x * 4 + r;
    if (row < nrows) Yl[r][c] = y[(size_t)row * DD + c];
    __syncthreads();
    if (row >= nrows) return;
    float acc = INIT ? b2[c] : z[(size_t)row * DD + c];
#pragma unroll
    for (int l = 0; l < DD; l++) acc = fmaf(Yl[r][l], Wl[l * DD + c], acc);
    z[(size_t)row * DD + c] = acc;
}

__global__ void k_l2norm(float* __restrict__ y, int nrows) {
    int gid = blockIdx.x * blockDim.x + threadIdx.x;
    int row = gid >> 6, f = gid & 63;
    if (row >= nrows) return;
    float v = y[(size_t)row * DD + f];
    float ss = v * v;
#pragma unroll
    for (int off = 32; off > 0; off >>= 1) ss += __shfl_xor(ss, off, 64);
    float n = sqrtf(ss);
    float inv = 1.0f / fmaxf(n, 1e-12f);
    y[(size_t)row * DD + f] = v * inv;
}

__global__ void k_axpy(float* __restrict__ out, const float* __restrict__ in, int n) {
    int i = blockIdx.x * blockDim.x + threadIdx.x;
    if (i < n) out[i] += in[i];
}

__global__ void k_combine(const float* __restrict__ z, const float* __restrict__ gs,
                          const float* __restrict__ ts, float* __restrict__ x,
                          float* __restrict__ acc, int n) {
    int i = blockIdx.x * blockDim.x + threadIdx.x;
    if (i >= n) return;
    float g = 1.0f / (1.0f + __expf(-z[i]));
    float xn = g * gs[i] + (1.0f - g) * ts[i];
    x[i] = xn;
    acc[i] += xn;
}

// ---------------- host launcher ----------------

extern "C" void kernel_launch(void* const* d_in, const int* in_sizes, int n_in,
                              void* d_out, int out_size, void* d_ws, size_t ws_size,
                              hipStream_t stream) {
    const float* user_emb = (const float*)d_in[0];
    const float* item_emb = (const float*)d_in[1];
    const float* intents  = (const float*)d_in[2];
    const float* W2       = (const float*)d_in[3];
    const float* b2       = (const float*)d_in[4];
    const float* uu_w     = (const float*)d_in[5];
    const float* ii_w     = (const float*)d_in[6];
    const int*   ui_u     = (const int*)d_in[7];
    const int*   ui_i     = (const int*)d_in[8];
    const int*   uu_h     = (const int*)d_in[9];
    const int*   uu_t     = (const int*)d_in[10];
    const int*   ii_h     = (const int*)d_in[11];
    const int*   ii_t     = (const int*)d_in[12];
    float* acc = (float*)d_out;

    char* pw = (char*)d_ws;
    auto alloc = [&](size_t nbytes) -> float* {
        float* r = (float*)pw;
        pw += (nbytes + 255) & ~(size_t)255;
        return r;
    };
    float* x    = alloc((size_t)NN * DD * 4);
    float* gs   = alloc((size_t)NN * DD * 4);
    float* ts   = alloc((size_t)NN * DD * 4);
    float* y    = alloc((size_t)NN * DD * 4);
    float* z    = alloc((size_t)NN * DD * 4);
    float* dinv = alloc((size_t)NN * 4);
    float* iuu  = alloc((size_t)NU * 4);
    float* iii  = alloc((size_t)NI * 4);
    float* aggu = alloc((size_t)NU * KK * 4);
    float* aggi = alloc((size_t)NI * KK * 4);
    float* wa   = alloc((size_t)EUI * 4);
    float* wb   = alloc((size_t)EUI * 4);
    float* rsa  = alloc((size_t)NU * 4);
    float* rsb  = alloc((size_t)NU * 4);

    const int B = 256;

    // ---- x-independent precompute ----
    hipMemsetAsync(dinv, 0, (size_t)NN * 4, stream);
    k_deg<<<cdiv(EUI, B), B, 0, stream>>>(ui_u, ui_i, dinv);
    k_dinv<<<cdiv(NN, B), B, 0, stream>>>(dinv, NN);
    hipMemsetAsync(iuu, 0, (size_t)NU * 4, stream);
    k_rowsum<<<cdiv(EUU, B), B, 0, stream>>>(uu_h, uu_w, iuu, EUU);
    k_invert<<<cdiv(NU, B), B, 0, stream>>>(iuu, NU);
    hipMemsetAsync(iii, 0, (size_t)NI * 4, stream);
    k_rowsum<<<cdiv(EII, B), B, 0, stream>>>(ii_h, ii_w, iii, EII);
    k_invert<<<cdiv(NI, B), B, 0, stream>>>(iii, NI);

    hipMemcpyAsync(x, user_emb, (size_t)NU * DD * 4, hipMemcpyDeviceToDevice, stream);
    hipMemcpyAsync(x + (size_t)NU * DD, item_emb, (size_t)NI * DD * 4, hipMemcpyDeviceToDevice, stream);
    hipMemcpyAsync(acc, x, (size_t)NN * DD * 4, hipMemcpyDeviceToDevice, stream);

    for (int layer = 0; layer < 2; ++layer) {
        // ---- g1 = embed11(x) -> gs; z = b2 + g1 @ W2[0:64] ----
        hipMemsetAsync(gs, 0, (size_t)NN * DD * 4, stream);
        k_spmm_ui_sym<<<cdiv((long)EUI * 64, B), B, 0, stream>>>(ui_u, ui_i, dinv, x, gs);
        k_gate_gemm<true><<<cdiv(NN, 4), B, 0, stream>>>(gs, W2 + 0 * DD * DD, b2, z, NN);

        // ---- g2 = embed12(x) -> y; gs += y; z += y @ W2[64:128] ----
        hipMemsetAsync(y, 0, (size_t)NN * DD * 4, stream);
        k_spmm_w<<<cdiv((long)EUU * 64, B), B, 0, stream>>>(uu_h, uu_t, uu_w, iuu, x, y, EUU);
        k_spmm_w<<<cdiv((long)EII * 64, B), B, 0, stream>>>(ii_h, ii_t, ii_w, iii,
                                                            x + (size_t)NU * DD, y + (size_t)NU * DD, EII);
        k_axpy<<<cdiv((long)NN * DD, B), B, 0, stream>>>(gs, y, NN * DD);
        k_gate_gemm<false><<<cdiv(NN, 4), B, 0, stream>>>(y, W2 + 1 * DD * DD, b2, z, NN);

        // ---- t1 = embed21(x,x) -> ts; z += t1 @ W2[128:192] ----
        hipMemsetAsync(aggu, 0, (size_t)NU * KK * 4, stream);
        hipMemsetAsync(aggi, 0, (size_t)NI * KK * 4, stream);
        k_intent_a<true><<<cdiv(EUI, B), B, 0, stream>>>(ui_u, ui_i, NU, x, intents, aggu, aggi, EUI);
        k_invert<<<cdiv(NU * KK, B), B, 0, stream>>>(aggu, NU * KK);
        k_invert<<<cdiv(NI * KK, B), B, 0, stream>>>(aggi, NI * KK);
        hipMemsetAsync(rsa, 0, (size_t)NU * 4, stream);
        hipMemsetAsync(rsb, 0, (size_t)NU * 4, stream);
        k_intent_c<true><<<cdiv(EUI, B), B, 0, stream>>>(ui_u, ui_i, NU, x, intents, aggu, aggi,
                                                         wa, wb, rsa, rsb, EUI);
        k_invert<<<cdiv(NU, B), B, 0, stream>>>(rsa, NU);
        k_invert<<<cdiv(NI, B), B, 0, stream>>>(rsb, NI);
        hipMemsetAsync(ts, 0, (size_t)NN * DD * 4, stream);
        k_spmm_ui_t1<<<cdiv((long)EUI * 64, B), B, 0, stream>>>(ui_u, ui_i, wa, wb, rsa, rsb, x, ts);
        k_l2norm<<<cdiv((long)NN * 64, B), B, 0, stream>>>(ts, NN);
        k_gate_gemm<false><<<cdiv(NN, 4), B, 0, stream>>>(ts, W2 + 2 * DD * DD, b2, z, NN);

        // ---- t2 = embed22(x,x) -> y; ts += y; z += y @ W2[192:256] ----
        hipMemsetAsync(y, 0, (size_t)NN * DD * 4, stream);
        // uu half
        hipMemsetAsync(aggu, 0, (size_t)NU * KK * 4, stream);
        k_intent_a<false><<<cdiv(EUU, B), B, 0, stream>>>(uu_h, uu_t, 0, x, intents, aggu,
                                                          (float*)nullptr, EUU);
        k_invert<<<cdiv(NU * KK, B), B, 0, stream>>>(aggu, NU * KK);
        hipMemsetAsync(rsa, 0, (size_t)NU * 4, stream);
        k_intent_c<false><<<cdiv(EUU, B), B, 0, stream>>>(uu_h, uu_t, 0, x, intents, aggu,
                                                          (const float*)nullptr, wa, (float*)nullptr,
                                                          rsa, (float*)nullptr, EUU);
        k_invert<<<cdiv(NU, B), B, 0, stream>>>(rsa, NU);
        k_spmm_w<<<cdiv((long)EUU * 64, B), B, 0, stream>>>(uu_h, uu_t, wa, rsa, x, y, EUU);
        // ii half
        hipMemsetAsync(aggi, 0, (size_t)NI * KK * 4, stream);
        k_intent_a<false><<<cdiv(EII, B), B, 0, stream>>>(ii_h, ii_t, 0, x + (size_t)NU * DD,
                                                          intents, aggi, (float*)nullptr, EII);
        k_invert<<<cdiv(NI * KK, B), B, 0, stream>>>(aggi, NI * KK);
        hipMemsetAsync(rsb, 0, (size_t)NU * 4, stream);
        k_intent_c<false><<<cdiv(EII, B), B, 0, stream>>>(ii_h, ii_t, 0, x + (size_t)NU * DD,
                                                          intents, aggi, (const float*)nullptr,
                                                          wa, (float*)nullptr, rsb, (float*)nullptr, EII);
        k_invert<<<cdiv(NI, B), B, 0, stream>>>(rsb, NI);
        k_spmm_w<<<cdiv((long)EII * 64, B), B, 0, stream>>>(ii_h, ii_t, wa, rsb,
                                                            x + (size_t)NU * DD, y + (size_t)NU * DD, EII);
        k_l2norm<<<cdiv((long)NN * 64, B), B, 0, stream>>>(y, NN);
        k_axpy<<<cdiv((long)NN * DD, B), B, 0, stream>>>(ts, y, NN * DD);
        k_gate_gemm<false><<<cdiv(NN, 4), B, 0, stream>>>(y, W2 + 3 * DD * DD, b2, z, NN);

        // ---- combine: x = gate*(g1+g2) + (1-gate)*(t1+t2); acc += x ----
        k_combine<<<cdiv((long)NN * DD, B), B, 0, stream>>>(z, gs, ts, x, acc, NN * DD);
    }
}

// Round 2
// 7018.427 us; speedup vs baseline: 2.0551x; 2.0551x over previous
//
#include <hip/hip_runtime.h>

#define NU 100000
#define NI 50000
#define NN 150000
#define DD 64
#define KK 32
#define EUI 1000000
#define EUU 500000
#define EII 500000

static inline int cdiv(long a, int b) { return (int)((a + b - 1) / b); }

// ---------------- CSR build ----------------

__global__ void k_count(const int* __restrict__ h, int* __restrict__ cnt, int E) {
    int e = blockIdx.x * blockDim.x + threadIdx.x;
    if (e < E) atomicAdd(&cnt[h[e]], 1);
}

// single-block exclusive scan: rp[0..n] from cnt[0..n-1]
__global__ __launch_bounds__(1024) void k_scan(const int* __restrict__ cnt,
                                               int* __restrict__ rp, int n) {
    __shared__ int wsum[16];
    __shared__ int carry_s;
    int tid = threadIdx.x;
    int lane = tid & 63, wid = tid >> 6;
    if (tid == 0) carry_s = 0;
    __syncthreads();
    for (int base = 0; base < n; base += 1024) {
        int i = base + tid;
        int v = (i < n) ? cnt[i] : 0;
        int s = v;
#pragma unroll
        for (int off = 1; off < 64; off <<= 1) {
            int t = __shfl_up(s, off, 64);
            if (lane >= off) s += t;
        }
        if (lane == 63) wsum[wid] = s;
        __syncthreads();
        int woff = 0, total = 0;
#pragma unroll
        for (int w = 0; w < 16; w++) { int ws = wsum[w]; total += ws; if (w < wid) woff += ws; }
        int carry = carry_s;
        if (i < n) rp[i] = carry + woff + (s - v);
        __syncthreads();
        if (tid == 0) carry_s = carry + total;
        __syncthreads();
    }
    if (tid == 0) rp[n] = carry_s;
}

__global__ void k_scatter(const int* __restrict__ h, const int* __restrict__ rp,
                          int* __restrict__ cur, int* __restrict__ lst, int E) {
    int e = blockIdx.x * blockDim.x + threadIdx.x;
    if (e >= E) return;
    int r = h[e];
    int p = rp[r] + atomicAdd(&cur[r], 1);
    lst[p] = e;
}

__global__ void k_dinv(const int* __restrict__ rpu, const int* __restrict__ rpi,
                       float* __restrict__ dinv) {
    int t = blockIdx.x * blockDim.x + threadIdx.x;
    if (t >= NN) return;
    int deg = (t < NU) ? rpu[t + 1] - rpu[t] : rpi[t - NU + 1] - rpi[t - NU];
    dinv[t] = deg > 0 ? rsqrtf((float)deg) : 0.0f;
}

// out[r] = 1 / sum_e w[lst[e]]  (0 if sum == 0)
__global__ void k_rowsum_inv(const int* __restrict__ rp, const int* __restrict__ lst,
                             const float* __restrict__ w, float* __restrict__ out, int n) {
    int r = blockIdx.x * blockDim.x + threadIdx.x;
    if (r >= n) return;
    float s = 0.f;
    int e1 = rp[r + 1];
    for (int e = rp[r]; e < e1; e++) s += w[lst[e]];
    out[r] = (s != 0.0f) ? 1.0f / s : 0.0f;
}

// ---------------- CSR SpMM (wave per row, lane per feature) ----------------
// MODE 0: val = dinv[row_g]*dinv[col]   MODE 1: val = wsrc[eid], row scaled by invr[r]
template <int MODE, bool L2N>
__global__ void k_spmm_csr(const int* __restrict__ rp, const int* __restrict__ lst,
                           const int* __restrict__ tails, int tail_off, int row_off,
                           const float* __restrict__ wsrc, const float* __restrict__ invr,
                           const float* __restrict__ dinv, const float* __restrict__ x,
                           float* __restrict__ out, int nrows) {
    int r = blockIdx.x * 4 + (threadIdx.x >> 6);
    int lane = threadIdx.x & 63;
    if (r >= nrows) return;
    int row_g = r + row_off;
    float acc = 0.f;
    float dh = (MODE == 0) ? dinv[row_g] : 0.f;
    int e1 = rp[r + 1];
    for (int e = rp[r]; e < e1; e++) {
        int eid = lst[e];
        int col = tails[eid] + tail_off;
        float val = (MODE == 0) ? dh * dinv[col] : wsrc[eid];
        acc += val * x[(size_t)col * DD + lane];
    }
    if (MODE == 1) acc *= invr[r];
    if (L2N) {
        float ss = acc * acc;
#pragma unroll
        for (int off = 32; off > 0; off >>= 1) ss += __shfl_xor(ss, off, 64);
        acc *= 1.0f / fmaxf(sqrtf(ss), 1e-12f);
    }
    out[(size_t)row_g * DD + lane] = acc;
}

// ---------------- intent aggregation (node-parallel, no atomics) ----------------
// recip[r][k] = 1 / sum_{edges of r} alpha_e * dist_e[k]   (0 where sum == 0)
__global__ __launch_bounds__(256) void k_intent_agg(
        const int* __restrict__ rp, const int* __restrict__ lst,
        const int* __restrict__ tails, int head_base, int tail_base,
        const float* __restrict__ x, const float* __restrict__ intents,
        float* __restrict__ recip, int n) {
    __shared__ float Wl[DD * KK];
    for (int idx = threadIdx.x; idx < DD * KK; idx += blockDim.x) Wl[idx] = intents[idx];
    __syncthreads();
    int r = blockIdx.x * blockDim.x + threadIdx.x;
    if (r >= n) return;
    const float4* hp = (const float4*)(x + (size_t)(r + head_base) * DD);
    float4 h4[16];
#pragma unroll
    for (int j = 0; j < 16; j++) h4[j] = hp[j];
    float agg[KK];
#pragma unroll
    for (int k = 0; k < KK; k++) agg[k] = 0.f;
    int e1 = rp[r + 1];
    for (int e = rp[r]; e < e1; e++) {
        int eid = lst[e];
        int col = tails[eid] + tail_base;
        const float4* tp = (const float4*)(x + (size_t)col * DD);
        float logit[KK];
#pragma unroll
        for (int k = 0; k < KK; k++) logit[k] = 0.f;
        float dot = 0.f;
#pragma unroll 4
        for (int l4 = 0; l4 < 16; l4++) {
            float4 t4 = tp[l4];
            float p0 = h4[l4].x * t4.x, p1 = h4[l4].y * t4.y;
            float p2 = h4[l4].z * t4.z, p3 = h4[l4].w * t4.w;
            dot += p0 + p1 + p2 + p3;
            const float* w = &Wl[l4 * 4 * KK];
#pragma unroll
            for (int k = 0; k < KK; k++)
                logit[k] += p0 * w[k] + p1 * w[KK + k] + p2 * w[2 * KK + k] + p3 * w[3 * KK + k];
        }
        float m = logit[0];
#pragma unroll
        for (int k = 1; k < KK; k++) m = fmaxf(m, logit[k]);
        float ssum = 0.f;
#pragma unroll
        for (int k = 0; k < KK; k++) { float ev = __expf(logit[k] - m); logit[k] = ev; ssum += ev; }
        float asc = 0.5f * (dot + 1.0f) / ssum;   // alpha / softmax-denominator
#pragma unroll
        for (int k = 0; k < KK; k++) agg[k] += asc * logit[k];
    }
    float* o = recip + (size_t)r * KK;
#pragma unroll
    for (int k = 0; k < KK; k++) { float a = agg[k]; o[k] = (a != 0.f) ? 1.0f / a : 0.f; }
}

// ---------------- per-edge intent weight (streaming writes, no atomics) ----------------
template <bool DUAL>
__global__ __launch_bounds__(256) void k_intent_w(
        const int* __restrict__ eh, const int* __restrict__ et, int toff,
        const float* __restrict__ feat, const float* __restrict__ intents,
        const float* __restrict__ recip_a, const float* __restrict__ recip_b,
        float* __restrict__ w_a, float* __restrict__ w_b, int E) {
    __shared__ float Wl[DD * KK];
    for (int idx = threadIdx.x; idx < DD * KK; idx += blockDim.x) Wl[idx] = intents[idx];
    __syncthreads();
    int e = blockIdx.x * blockDim.x + threadIdx.x;
    if (e >= E) return;
    int hn = eh[e], tn = et[e];
    const float4* hp = (const float4*)(feat + (size_t)hn * DD);
    const float4* tp = (const float4*)(feat + (size_t)(tn + toff) * DD);
    float logit[KK];
#pragma unroll
    for (int k = 0; k < KK; k++) logit[k] = 0.f;
    float dot = 0.f;
#pragma unroll 4
    for (int l4 = 0; l4 < 16; l4++) {
        float4 h4 = hp[l4], t4 = tp[l4];
        float p0 = h4.x * t4.x, p1 = h4.y * t4.y, p2 = h4.z * t4.z, p3 = h4.w * t4.w;
        dot += p0 + p1 + p2 + p3;
        const float* w = &Wl[l4 * 4 * KK];
#pragma unroll
        for (int k = 0; k < KK; k++)
            logit[k] += p0 * w[k] + p1 * w[KK + k] + p2 * w[2 * KK + k] + p3 * w[3 * KK + k];
    }
    float m = logit[0];
#pragma unroll
    for (int k = 1; k < KK; k++) m = fmaxf(m, logit[k]);
    float ssum = 0.f;
#pragma unroll
    for (int k = 0; k < KK; k++) { float ev = __expf(logit[k] - m); logit[k] = ev; ssum += ev; }
    float alpha = 0.5f * (dot + 1.0f);
    float inv_sK = 1.0f / (ssum * (float)KK);
    const float* ra = recip_a + (size_t)hn * KK;
    float sa = 0.f;
#pragma unroll
    for (int k = 0; k < KK; k++) sa += logit[k] * ra[k];
    w_a[e] = alpha * sa * inv_sK;
    if (DUAL) {
        const float* rb = recip_b + (size_t)tn * KK;
        float sb = 0.f;
#pragma unroll
        for (int k = 0; k < KK; k++) sb += logit[k] * rb[k];
        w_b[e] = alpha * sb * inv_sK;
    }
}

// ---------------- dense kernels ----------------

template <bool INIT>
__global__ void k_gate_gemm(const float* __restrict__ y, const float* __restrict__ W2blk,
                            const float* __restrict__ b2, float* __restrict__ z, int nrows) {
    __shared__ float Wl[DD * DD];
    __shared__ float Yl[4][DD];
    for (int idx = threadIdx.x; idx < DD * DD; idx += blockDim.x) Wl[idx] = W2blk[idx];
    int r = threadIdx.x >> 6, c = threadIdx.x & 63;
    int row = blockIdx.x * 4 + r;
    if (row < nrows) Yl[r][c] = y[(size_t)row * DD + c];
    __syncthreads();
    if (row >= nrows) return;
    float acc = INIT ? b2[c] : z[(size_t)row * DD + c];
#pragma unroll
    for (int l = 0; l < DD; l++) acc = fmaf(Yl[r][l], Wl[l * DD + c], acc);
    z[(size_t)row * DD + c] = acc;
}

__global__ void k_axpy(float* __restrict__ out, const float* __restrict__ in, int n) {
    int i = blockIdx.x * blockDim.x + threadIdx.x;
    if (i < n) out[i] += in[i];
}

__global__ void k_combine(const float* __restrict__ z, const float* __restrict__ gs,
                          const float* __restrict__ ts, float* __restrict__ x,
                          float* __restrict__ acc, int n) {
    int i = blockIdx.x * blockDim.x + threadIdx.x;
    if (i >= n) return;
    float g = 1.0f / (1.0f + __expf(-z[i]));
    float xn = g * gs[i] + (1.0f - g) * ts[i];
    x[i] = xn;
    acc[i] += xn;
}

// ---------------- host launcher ----------------

extern "C" void kernel_launch(void* const* d_in, const int* in_sizes, int n_in,
                              void* d_out, int out_size, void* d_ws, size_t ws_size,
                              hipStream_t stream) {
    const float* user_emb = (const float*)d_in[0];
    const float* item_emb = (const float*)d_in[1];
    const float* intents  = (const float*)d_in[2];
    const float* W2       = (const float*)d_in[3];
    const float* b2       = (const float*)d_in[4];
    const float* uu_w     = (const float*)d_in[5];
    const float* ii_w     = (const float*)d_in[6];
    const int*   ui_u     = (const int*)d_in[7];
    const int*   ui_i     = (const int*)d_in[8];
    const int*   uu_h     = (const int*)d_in[9];
    const int*   uu_t     = (const int*)d_in[10];
    const int*   ii_h     = (const int*)d_in[11];
    const int*   ii_t     = (const int*)d_in[12];
    float* acc = (float*)d_out;

    char* pw = (char*)d_ws;
    auto allocf = [&](size_t nelem) -> float* {
        float* r = (float*)pw;
        pw += (nelem * 4 + 255) & ~(size_t)255;
        return r;
    };
    auto alloci = [&](size_t nelem) -> int* {
        int* r = (int*)pw;
        pw += (nelem * 4 + 255) & ~(size_t)255;
        return r;
    };
    float* x      = allocf((size_t)NN * DD);
    float* gs     = allocf((size_t)NN * DD);
    float* ts     = allocf((size_t)NN * DD);
    float* y      = allocf((size_t)NN * DD);
    float* z      = allocf((size_t)NN * DD);
    float* dinv   = allocf(NN);
    float* iuu    = allocf(NU);
    float* iii    = allocf(NI);
    float* recipu = allocf((size_t)NU * KK);
    float* recipi = allocf((size_t)NI * KK);
    float* wa     = allocf(EUI);
    float* wb     = allocf(EUI);
    float* rsa    = allocf(NU);
    float* rsb    = allocf(NU);
    int* rp_u   = alloci(NU + 1);
    int* rp_i   = alloci(NI + 1);
    int* rp_uu  = alloci(NU + 1);
    int* rp_ii  = alloci(NI + 1);
    int* lst_u  = alloci(EUI);
    int* lst_i  = alloci(EUI);
    int* lst_uu = alloci(EUU);
    int* lst_ii = alloci(EII);
    int* cur    = alloci(NU);

    const int B = 256;

    auto build_csr = [&](const int* h, int E, int n, int* rp, int* lst) {
        hipMemsetAsync(cur, 0, (size_t)n * 4, stream);
        k_count<<<cdiv(E, B), B, 0, stream>>>(h, cur, E);
        k_scan<<<1, 1024, 0, stream>>>(cur, rp, n);
        hipMemsetAsync(cur, 0, (size_t)n * 4, stream);
        k_scatter<<<cdiv(E, B), B, 0, stream>>>(h, rp, cur, lst, E);
    };

    build_csr(ui_u, EUI, NU, rp_u, lst_u);
    build_csr(ui_i, EUI, NI, rp_i, lst_i);
    build_csr(uu_h, EUU, NU, rp_uu, lst_uu);
    build_csr(ii_h, EII, NI, rp_ii, lst_ii);
    k_dinv<<<cdiv(NN, B), B, 0, stream>>>(rp_u, rp_i, dinv);
    k_rowsum_inv<<<cdiv(NU, B), B, 0, stream>>>(rp_uu, lst_uu, uu_w, iuu, NU);
    k_rowsum_inv<<<cdiv(NI, B), B, 0, stream>>>(rp_ii, lst_ii, ii_w, iii, NI);

    hipMemcpyAsync(x, user_emb, (size_t)NU * DD * 4, hipMemcpyDeviceToDevice, stream);
    hipMemcpyAsync(x + (size_t)NU * DD, item_emb, (size_t)NI * DD * 4, hipMemcpyDeviceToDevice, stream);
    hipMemcpyAsync(acc, x, (size_t)NN * DD * 4, hipMemcpyDeviceToDevice, stream);

    for (int layer = 0; layer < 2; ++layer) {
        // ---- g1 = embed11(x) -> gs ----
        k_spmm_csr<0, false><<<cdiv(NU, 4), B, 0, stream>>>(rp_u, lst_u, ui_i, NU, 0,
                                                            nullptr, nullptr, dinv, x, gs, NU);
        k_spmm_csr<0, false><<<cdiv(NI, 4), B, 0, stream>>>(rp_i, lst_i, ui_u, 0, NU,
                                                            nullptr, nullptr, dinv, x, gs, NI);
        k_gate_gemm<true><<<cdiv(NN, 4), B, 0, stream>>>(gs, W2, b2, z, NN);

        // ---- g2 = embed12(x) -> y; gs += y ----
        k_spmm_csr<1, false><<<cdiv(NU, 4), B, 0, stream>>>(rp_uu, lst_uu, uu_t, 0, 0,
                                                            uu_w, iuu, nullptr, x, y, NU);
        k_spmm_csr<1, false><<<cdiv(NI, 4), B, 0, stream>>>(rp_ii, lst_ii, ii_t, NU, NU,
                                                            ii_w, iii, nullptr, x, y, NI);
        k_axpy<<<cdiv((long)NN * DD, B), B, 0, stream>>>(gs, y, NN * DD);
        k_gate_gemm<false><<<cdiv(NN, 4), B, 0, stream>>>(y, W2 + DD * DD, b2, z, NN);

        // ---- t1 = embed21(x,x) -> ts ----
        k_intent_agg<<<cdiv(NU, B), B, 0, stream>>>(rp_u, lst_u, ui_i, 0, NU, x, intents, recipu, NU);
        k_intent_agg<<<cdiv(NI, B), B, 0, stream>>>(rp_i, lst_i, ui_u, NU, 0, x, intents, recipi, NI);
        k_intent_w<true><<<cdiv(EUI, B), B, 0, stream>>>(ui_u, ui_i, NU, x, intents,
                                                         recipu, recipi, wa, wb, EUI);
        k_rowsum_inv<<<cdiv(NU, B), B, 0, stream>>>(rp_u, lst_u, wa, rsa, NU);
        k_rowsum_inv<<<cdiv(NI, B), B, 0, stream>>>(rp_i, lst_i, wb, rsb, NI);
        k_spmm_csr<1, true><<<cdiv(NU, 4), B, 0, stream>>>(rp_u, lst_u, ui_i, NU, 0,
                                                           wa, rsa, nullptr, x, ts, NU);
        k_spmm_csr<1, true><<<cdiv(NI, 4), B, 0, stream>>>(rp_i, lst_i, ui_u, 0, NU,
                                                           wb, rsb, nullptr, x, ts, NI);
        k_gate_gemm<false><<<cdiv(NN, 4), B, 0, stream>>>(ts, W2 + 2 * DD * DD, b2, z, NN);

        // ---- t2 = embed22(x,x) -> y; ts += y ----
        k_intent_agg<<<cdiv(NU, B), B, 0, stream>>>(rp_uu, lst_uu, uu_t, 0, 0, x, intents, recipu, NU);
        k_intent_w<false><<<cdiv(EUU, B), B, 0, stream>>>(uu_h, uu_t, 0, x, intents,
                                                          recipu, nullptr, wa, nullptr, EUU);
        k_rowsum_inv<<<cdiv(NU, B), B, 0, stream>>>(rp_uu, lst_uu, wa, rsa, NU);
        k_spmm_csr<1, true><<<cdiv(NU, 4), B, 0, stream>>>(rp_uu, lst_uu, uu_t, 0, 0,
                                                           wa, rsa, nullptr, x, y, NU);
        k_intent_agg<<<cdiv(NI, B), B, 0, stream>>>(rp_ii, lst_ii, ii_t, NU, NU, x, intents, recipi, NI);
        k_intent_w<false><<<cdiv(EII, B), B, 0, stream>>>(ii_h, ii_t, 0, x + (size_t)NU * DD,
                                                          intents, recipi, nullptr, wa, nullptr, EII);
        k_rowsum_inv<<<cdiv(NI, B), B, 0, stream>>>(rp_ii, lst_ii, wa, rsb, NI);
        k_spmm_csr<1, true><<<cdiv(NI, 4), B, 0, stream>>>(rp_ii, lst_ii, ii_t, NU, NU,
                                                           wa, rsb, nullptr, x, y, NI);
        k_axpy<<<cdiv((long)NN * DD, B), B, 0, stream>>>(ts, y, NN * DD);
        k_gate_gemm<false><<<cdiv(NN, 4), B, 0, stream>>>(y, W2 + 3 * DD * DD, b2, z, NN);

        // ---- combine ----
        k_combine<<<cdiv((long)NN * DD, B), B, 0, stream>>>(z, gs, ts, x, acc, NN * DD);
    }
}

// Round 4
// 4121.918 us; speedup vs baseline: 3.4992x; 1.7027x over previous
//
#include <hip/hip_runtime.h>
#include <hip/hip_fp16.h>

#define NU 100000
#define NI 50000
#define NN 150000
#define DD 64
#define KK 32
#define EUI 1000000
#define EUU 500000
#define EII 500000

static inline int cdiv(long a, int b) { return (int)((a + b - 1) / b); }

// ---------------- CSR build ----------------

__global__ void k_count(const int* __restrict__ h, int* __restrict__ cnt, int E) {
    int e = blockIdx.x * blockDim.x + threadIdx.x;
    if (e < E) atomicAdd(&cnt[h[e]], 1);
}

__global__ __launch_bounds__(1024) void k_scan(const int* __restrict__ cnt,
                                               int* __restrict__ rp, int n) {
    __shared__ int wsum[16];
    __shared__ int carry_s;
    int tid = threadIdx.x;
    int lane = tid & 63, wid = tid >> 6;
    if (tid == 0) carry_s = 0;
    __syncthreads();
    for (int base = 0; base < n; base += 1024) {
        int i = base + tid;
        int v = (i < n) ? cnt[i] : 0;
        int s = v;
#pragma unroll
        for (int off = 1; off < 64; off <<= 1) {
            int t = __shfl_up(s, off, 64);
            if (lane >= off) s += t;
        }
        if (lane == 63) wsum[wid] = s;
        __syncthreads();
        int woff = 0, total = 0;
#pragma unroll
        for (int w = 0; w < 16; w++) { int ws = wsum[w]; total += ws; if (w < wid) woff += ws; }
        int carry = carry_s;
        if (i < n) rp[i] = carry + woff + (s - v);
        __syncthreads();
        if (tid == 0) carry_s = carry + total;
        __syncthreads();
    }
    if (tid == 0) rp[n] = carry_s;
}

__global__ void k_scatter(const int* __restrict__ h, const int* __restrict__ rp,
                          int* __restrict__ cur, int* __restrict__ lst, int E) {
    int e = blockIdx.x * blockDim.x + threadIdx.x;
    if (e >= E) return;
    int r = h[e];
    int p = rp[r] + atomicAdd(&cur[r], 1);
    lst[p] = e;
}

__global__ void k_dinv(const int* __restrict__ rpu, const int* __restrict__ rpi,
                       float* __restrict__ dinv) {
    int t = blockIdx.x * blockDim.x + threadIdx.x;
    if (t >= NN) return;
    int deg = (t < NU) ? rpu[t + 1] - rpu[t] : rpi[t - NU + 1] - rpi[t - NU];
    dinv[t] = deg > 0 ? rsqrtf((float)deg) : 0.0f;
}

__global__ void k_rowsum_inv(const int* __restrict__ rp, const int* __restrict__ lst,
                             const float* __restrict__ w, float* __restrict__ out, int n) {
    int r = blockIdx.x * blockDim.x + threadIdx.x;
    if (r >= n) return;
    float s = 0.f;
    int e1 = rp[r + 1];
    for (int e = rp[r]; e < e1; e++) s += w[lst[e]];
    out[r] = (s != 0.0f) ? 1.0f / s : 0.0f;
}

// Wd_g = W2[0:64] - W2[64:128]; Wd_t = W2[128:192] - W2[192:256]
__global__ void k_wdiff(const float* __restrict__ W2, float* __restrict__ Wd_g,
                        float* __restrict__ Wd_t) {
    int i = blockIdx.x * blockDim.x + threadIdx.x;
    if (i >= DD * DD) return;
    Wd_g[i] = W2[i] - W2[DD * DD + i];
    Wd_t[i] = W2[2 * DD * DD + i] - W2[3 * DD * DD + i];
}

// ---------------- CSR SpMM (wave per row, lane per feature) ----------------
// VAL 0: val = dinv[row_g]*dinv[col]
// VAL 1: val = wsrc[eid] (edge order); row scaled by invr[r]
// VAL 2: val = wsrc[p]   (CSR order);  row scaled by invr[r]
template <int VAL, bool L2N, bool ACC>
__global__ void k_spmm(const int* __restrict__ rp, const int* __restrict__ lst,
                       const int* __restrict__ tails, int tail_off, int row_off,
                       const float* __restrict__ wsrc, const float* __restrict__ invr,
                       const float* __restrict__ dinv, const float* __restrict__ x,
                       float* __restrict__ out, int nrows) {
    int r = blockIdx.x * 4 + (threadIdx.x >> 6);
    int lane = threadIdx.x & 63;
    if (r >= nrows) return;
    int row_g = r + row_off;
    float acc = 0.f;
    float dh = (VAL == 0) ? dinv[row_g] : 0.f;
    int e1 = rp[r + 1];
    for (int e = rp[r]; e < e1; e++) {
        int eid = lst[e];
        int col = tails[eid] + tail_off;
        float val = (VAL == 0) ? dh * dinv[col] : ((VAL == 1) ? wsrc[eid] : wsrc[e]);
        acc += val * x[(size_t)col * DD + lane];
    }
    if (VAL != 0) acc *= invr[r];
    if (L2N) {
        float ss = acc * acc;
#pragma unroll
        for (int off = 32; off > 0; off >>= 1) ss += __shfl_xor(ss, off, 64);
        acc *= 1.0f / fmaxf(sqrtf(ss), 1e-12f);
    }
    size_t oi = (size_t)row_g * DD + lane;
    if (ACC) out[oi] += acc; else out[oi] = acc;
}

// ---------------- pass A: per-edge contrib = alpha * dist, fp16, edge order ----------------

__global__ __launch_bounds__(256) void k_passA(
        const int* __restrict__ eh, const int* __restrict__ et, int toff,
        const float* __restrict__ feat, const float* __restrict__ intents,
        __half* __restrict__ c_out, int E) {
    __shared__ float Wl[DD * KK];
    for (int idx = threadIdx.x; idx < DD * KK; idx += blockDim.x) Wl[idx] = intents[idx];
    __syncthreads();
    int e = blockIdx.x * blockDim.x + threadIdx.x;
    if (e >= E) return;
    const float4* hp = (const float4*)(feat + (size_t)eh[e] * DD);
    const float4* tp = (const float4*)(feat + (size_t)(et[e] + toff) * DD);
    float logit[KK];
#pragma unroll
    for (int k = 0; k < KK; k++) logit[k] = 0.f;
    float dot = 0.f;
#pragma unroll 4
    for (int l4 = 0; l4 < 16; l4++) {
        float4 h4 = hp[l4], t4 = tp[l4];
        float p0 = h4.x * t4.x, p1 = h4.y * t4.y, p2 = h4.z * t4.z, p3 = h4.w * t4.w;
        dot += p0 + p1 + p2 + p3;
        const float* w = &Wl[l4 * 4 * KK];
#pragma unroll
        for (int k = 0; k < KK; k++)
            logit[k] += p0 * w[k] + p1 * w[KK + k] + p2 * w[2 * KK + k] + p3 * w[3 * KK + k];
    }
    float m = logit[0];
#pragma unroll
    for (int k = 1; k < KK; k++) m = fmaxf(m, logit[k]);
    float ssum = 0.f;
#pragma unroll
    for (int k = 0; k < KK; k++) { float ev = __expf(logit[k] - m); logit[k] = ev; ssum += ev; }
    float scale = 0.5f * (dot + 1.0f) / ssum;   // alpha / softmax denom
    uint4 pk[4];
    unsigned int* u = (unsigned int*)pk;
#pragma unroll
    for (int k2 = 0; k2 < 16; k2++) {
        __half2 hh = __floats2half2_rn(logit[2 * k2] * scale, logit[2 * k2 + 1] * scale);
        u[k2] = *reinterpret_cast<const unsigned int*>(&hh);
    }
    uint4* dst = (uint4*)(c_out + (size_t)e * KK);
#pragma unroll
    for (int q = 0; q < 4; q++) dst[q] = pk[q];
}

// ---------------- pass B+C fused: agg -> recip -> edge weights (CSR order) + inv rowsum ----
// 8 threads per node, each owns 4 k-indices; c gathered via lst (edge-id order).
__global__ __launch_bounds__(256) void k_passBC(const int* __restrict__ rp,
                                                const int* __restrict__ lst,
                                                const __half* __restrict__ c,
                                                float* __restrict__ w,
                                                float* __restrict__ rsinv, int n) {
    int gid = blockIdx.x * blockDim.x + threadIdx.x;
    int node = gid >> 3, j = gid & 7;
    if (node >= n) return;
    int p0 = rp[node], p1 = rp[node + 1];
    const uint2* cp = (const uint2*)c;   // 8 uint2 per 32-half row
    float4 agg = make_float4(0.f, 0.f, 0.f, 0.f);
    for (int p = p0; p < p1; p++) {
        uint2 v = cp[(size_t)lst[p] * 8 + j];
        float2 fa = __half22float2(*reinterpret_cast<const __half2*>(&v.x));
        float2 fb = __half22float2(*reinterpret_cast<const __half2*>(&v.y));
        agg.x += fa.x; agg.y += fa.y; agg.z += fb.x; agg.w += fb.y;
    }
    float4 rec;
    rec.x = (agg.x != 0.f) ? 1.f / agg.x : 0.f;
    rec.y = (agg.y != 0.f) ? 1.f / agg.y : 0.f;
    rec.z = (agg.z != 0.f) ? 1.f / agg.z : 0.f;
    rec.w = (agg.w != 0.f) ? 1.f / agg.w : 0.f;
    float rs = 0.f;
    for (int p = p0; p < p1; p++) {
        uint2 v = cp[(size_t)lst[p] * 8 + j];
        float2 fa = __half22float2(*reinterpret_cast<const __half2*>(&v.x));
        float2 fb = __half22float2(*reinterpret_cast<const __half2*>(&v.y));
        float dot = fa.x * rec.x + fa.y * rec.y + fb.x * rec.z + fb.y * rec.w;
        dot += __shfl_xor(dot, 1, 64);
        dot += __shfl_xor(dot, 2, 64);
        dot += __shfl_xor(dot, 4, 64);
        float wv = dot * (1.0f / KK);
        if (j == 0) w[p] = wv;
        rs += wv;
    }
    if (j == 0) rsinv[node] = (rs != 0.f) ? 1.f / rs : 0.f;
}

// ---------------- dense kernels ----------------

template <bool INIT>
__global__ void k_gate_gemm(const float* __restrict__ y, const float* __restrict__ W2blk,
                            const float* __restrict__ b2, float* __restrict__ z, int nrows) {
    __shared__ float Wl[DD * DD];
    __shared__ float Yl[4][DD];
    for (int idx = threadIdx.x; idx < DD * DD; idx += blockDim.x) Wl[idx] = W2blk[idx];
    int r = threadIdx.x >> 6, c = threadIdx.x & 63;
    int row = blockIdx.x * 4 + r;
    if (row < nrows) Yl[r][c] = y[(size_t)row * DD + c];
    __syncthreads();
    if (row >= nrows) return;
    float acc = INIT ? b2[c] : z[(size_t)row * DD + c];
#pragma unroll
    for (int l = 0; l < DD; l++) acc = fmaf(Yl[r][l], Wl[l * DD + c], acc);
    z[(size_t)row * DD + c] = acc;
}

__global__ void k_combine(const float* __restrict__ z, const float* __restrict__ gs,
                          const float* __restrict__ ts, float* __restrict__ x,
                          float* __restrict__ acc, int n) {
    int i = blockIdx.x * blockDim.x + threadIdx.x;
    if (i >= n) return;
    float g = 1.0f / (1.0f + __expf(-z[i]));
    float xn = g * gs[i] + (1.0f - g) * ts[i];
    x[i] = xn;
    acc[i] += xn;
}

// ---------------- host launcher ----------------

extern "C" void kernel_launch(void* const* d_in, const int* in_sizes, int n_in,
                              void* d_out, int out_size, void* d_ws, size_t ws_size,
                              hipStream_t stream) {
    const float* user_emb = (const float*)d_in[0];
    const float* item_emb = (const float*)d_in[1];
    const float* intents  = (const float*)d_in[2];
    const float* W2       = (const float*)d_in[3];
    const float* b2       = (const float*)d_in[4];
    const float* uu_w     = (const float*)d_in[5];
    const float* ii_w     = (const float*)d_in[6];
    const int*   ui_u     = (const int*)d_in[7];
    const int*   ui_i     = (const int*)d_in[8];
    const int*   uu_h     = (const int*)d_in[9];
    const int*   uu_t     = (const int*)d_in[10];
    const int*   ii_h     = (const int*)d_in[11];
    const int*   ii_t     = (const int*)d_in[12];
    float* acc = (float*)d_out;

    char* pw = (char*)d_ws;
    auto allocb = [&](size_t nbytes) -> char* {
        char* r = pw;
        pw += (nbytes + 255) & ~(size_t)255;
        return r;
    };
    // total ws use ~= 236 MB (round-2's proven footprint level)
    float* x    = (float*)allocb((size_t)NN * DD * 4);
    float* gs   = (float*)allocb((size_t)NN * DD * 4);
    float* ts   = (float*)allocb((size_t)NN * DD * 4);
    float* z    = (float*)allocb((size_t)NN * DD * 4);
    __half* c   = (__half*)allocb((size_t)EUI * KK * 2);   // 64 MB, reused UI/UU/II
    float* w    = (float*)allocb((size_t)EUI * 4);         // shared across sides
    float* rs   = (float*)allocb((size_t)NU * 4);          // shared across sides
    float* dinv = (float*)allocb((size_t)NN * 4);
    float* iuu  = (float*)allocb((size_t)NU * 4);
    float* iii  = (float*)allocb((size_t)NI * 4);
    float* Wd_g = (float*)allocb((size_t)DD * DD * 4);
    float* Wd_t = (float*)allocb((size_t)DD * DD * 4);
    int* rp_u   = (int*)allocb(((size_t)NU + 1) * 4);
    int* rp_i   = (int*)allocb(((size_t)NI + 1) * 4);
    int* rp_uu  = (int*)allocb(((size_t)NU + 1) * 4);
    int* rp_ii  = (int*)allocb(((size_t)NI + 1) * 4);
    int* lst_u  = (int*)allocb((size_t)EUI * 4);
    int* lst_i  = (int*)allocb((size_t)EUI * 4);
    int* lst_uu = (int*)allocb((size_t)EUU * 4);
    int* lst_ii = (int*)allocb((size_t)EII * 4);
    int* cur    = (int*)c;   // alias: CSR build finishes before c is used

    const int B = 256;

    auto build_csr = [&](const int* h, int E, int n, int* rp, int* lst) {
        hipMemsetAsync(cur, 0, (size_t)n * 4, stream);
        k_count<<<cdiv(E, B), B, 0, stream>>>(h, cur, E);
        k_scan<<<1, 1024, 0, stream>>>(cur, rp, n);
        hipMemsetAsync(cur, 0, (size_t)n * 4, stream);
        k_scatter<<<cdiv(E, B), B, 0, stream>>>(h, rp, cur, lst, E);
    };

    build_csr(ui_u, EUI, NU, rp_u, lst_u);
    build_csr(ui_i, EUI, NI, rp_i, lst_i);
    build_csr(uu_h, EUU, NU, rp_uu, lst_uu);
    build_csr(ii_h, EII, NI, rp_ii, lst_ii);
    k_dinv<<<cdiv(NN, B), B, 0, stream>>>(rp_u, rp_i, dinv);
    k_rowsum_inv<<<cdiv(NU, B), B, 0, stream>>>(rp_uu, lst_uu, uu_w, iuu, NU);
    k_rowsum_inv<<<cdiv(NI, B), B, 0, stream>>>(rp_ii, lst_ii, ii_w, iii, NI);
    k_wdiff<<<cdiv(DD * DD, B), B, 0, stream>>>(W2, Wd_g, Wd_t);

    hipMemcpyAsync(x, user_emb, (size_t)NU * DD * 4, hipMemcpyDeviceToDevice, stream);
    hipMemcpyAsync(x + (size_t)NU * DD, item_emb, (size_t)NI * DD * 4, hipMemcpyDeviceToDevice, stream);
    hipMemcpyAsync(acc, x, (size_t)NN * DD * 4, hipMemcpyDeviceToDevice, stream);

    for (int layer = 0; layer < 2; ++layer) {
        // ---- g1 -> gs (write); z = b2 + g1 @ (W0 - W1) ----
        k_spmm<0, false, false><<<cdiv(NU, 4), B, 0, stream>>>(rp_u, lst_u, ui_i, NU, 0,
                                                               nullptr, nullptr, dinv, x, gs, NU);
        k_spmm<0, false, false><<<cdiv(NI, 4), B, 0, stream>>>(rp_i, lst_i, ui_u, 0, NU,
                                                               nullptr, nullptr, dinv, x, gs, NI);
        k_gate_gemm<true><<<cdiv(NN, 4), B, 0, stream>>>(gs, Wd_g, b2, z, NN);

        // ---- g2 -> gs (+=); z += gs @ W1 ----
        k_spmm<1, false, true><<<cdiv(NU, 4), B, 0, stream>>>(rp_uu, lst_uu, uu_t, 0, 0,
                                                              uu_w, iuu, nullptr, x, gs, NU);
        k_spmm<1, false, true><<<cdiv(NI, 4), B, 0, stream>>>(rp_ii, lst_ii, ii_t, NU, NU,
                                                              ii_w, iii, nullptr, x, gs, NI);
        k_gate_gemm<false><<<cdiv(NN, 4), B, 0, stream>>>(gs, W2 + DD * DD, b2, z, NN);

        // ---- t1 -> ts (write, l2norm); z += t1 @ (W2 - W3) ----
        k_passA<<<cdiv(EUI, B), B, 0, stream>>>(ui_u, ui_i, NU, x, intents, c, EUI);
        k_passBC<<<cdiv((long)NU * 8, B), B, 0, stream>>>(rp_u, lst_u, c, w, rs, NU);
        k_spmm<2, true, false><<<cdiv(NU, 4), B, 0, stream>>>(rp_u, lst_u, ui_i, NU, 0,
                                                              w, rs, nullptr, x, ts, NU);
        k_passBC<<<cdiv((long)NI * 8, B), B, 0, stream>>>(rp_i, lst_i, c, w, rs, NI);
        k_spmm<2, true, false><<<cdiv(NI, 4), B, 0, stream>>>(rp_i, lst_i, ui_u, 0, NU,
                                                              w, rs, nullptr, x, ts, NI);
        k_gate_gemm<false><<<cdiv(NN, 4), B, 0, stream>>>(ts, Wd_t, b2, z, NN);

        // ---- t2 -> ts (+=, l2norm per row); z += ts @ W3 ----
        k_passA<<<cdiv(EUU, B), B, 0, stream>>>(uu_h, uu_t, 0, x, intents, c, EUU);
        k_passBC<<<cdiv((long)NU * 8, B), B, 0, stream>>>(rp_uu, lst_uu, c, w, rs, NU);
        k_spmm<2, true, true><<<cdiv(NU, 4), B, 0, stream>>>(rp_uu, lst_uu, uu_t, 0, 0,
                                                             w, rs, nullptr, x, ts, NU);
        k_passA<<<cdiv(EII, B), B, 0, stream>>>(ii_h, ii_t, 0, x + (size_t)NU * DD, intents, c, EII);
        k_passBC<<<cdiv((long)NI * 8, B), B, 0, stream>>>(rp_ii, lst_ii, c, w, rs, NI);
        k_spmm<2, true, true><<<cdiv(NI, 4), B, 0, stream>>>(rp_ii, lst_ii, ii_t, NU, NU,
                                                             w, rs, nullptr, x, ts, NI);
        k_gate_gemm<false><<<cdiv(NN, 4), B, 0, stream>>>(ts, W2 + 3 * DD * DD, b2, z, NN);

        // ---- combine ----
        k_combine<<<cdiv((long)NN * DD, B), B, 0, stream>>>(z, gs, ts, x, acc, NN * DD);
    }
}

// Round 5
// 3136.698 us; speedup vs baseline: 4.5982x; 1.3141x over previous
//
#include <hip/hip_runtime.h>
#include <hip/hip_fp16.h>

#define NU 100000
#define NI 50000
#define NN 150000
#define DD 64
#define KK 32
#define EUI 1000000
#define EUU 500000
#define EII 500000

static inline int cdiv(long a, int b) { return (int)((a + b - 1) / b); }

// ---------------- CSR build ----------------

__global__ void k_count(const int* __restrict__ h, int* __restrict__ cnt, int E) {
    int e = blockIdx.x * blockDim.x + threadIdx.x;
    if (e < E) atomicAdd(&cnt[h[e]], 1);
}

__global__ __launch_bounds__(1024) void k_scan(const int* __restrict__ cnt,
                                               int* __restrict__ rp, int n) {
    __shared__ int wsum[16];
    __shared__ int carry_s;
    int tid = threadIdx.x;
    int lane = tid & 63, wid = tid >> 6;
    if (tid == 0) carry_s = 0;
    __syncthreads();
    for (int base = 0; base < n; base += 1024) {
        int i = base + tid;
        int v = (i < n) ? cnt[i] : 0;
        int s = v;
#pragma unroll
        for (int off = 1; off < 64; off <<= 1) {
            int t = __shfl_up(s, off, 64);
            if (lane >= off) s += t;
        }
        if (lane == 63) wsum[wid] = s;
        __syncthreads();
        int woff = 0, total = 0;
#pragma unroll
        for (int w = 0; w < 16; w++) { int ws = wsum[w]; total += ws; if (w < wid) woff += ws; }
        int carry = carry_s;
        if (i < n) rp[i] = carry + woff + (s - v);
        __syncthreads();
        if (tid == 0) carry_s = carry + total;
        __syncthreads();
    }
    if (tid == 0) rp[n] = carry_s;
}

__global__ void k_scatter(const int* __restrict__ h, const int* __restrict__ rp,
                          int* __restrict__ cur, int* __restrict__ lst, int E) {
    int e = blockIdx.x * blockDim.x + threadIdx.x;
    if (e >= E) return;
    int r = h[e];
    int p = rp[r] + atomicAdd(&cur[r], 1);
    lst[p] = e;
}

__global__ void k_dinv(const int* __restrict__ rpu, const int* __restrict__ rpi,
                       float* __restrict__ dinv) {
    int t = blockIdx.x * blockDim.x + threadIdx.x;
    if (t >= NN) return;
    int deg = (t < NU) ? rpu[t + 1] - rpu[t] : rpi[t - NU + 1] - rpi[t - NU];
    dinv[t] = deg > 0 ? rsqrtf((float)deg) : 0.0f;
}

__global__ void k_rowsum_inv(const int* __restrict__ rp, const int* __restrict__ lst,
                             const float* __restrict__ w, float* __restrict__ out, int n) {
    int r = blockIdx.x * blockDim.x + threadIdx.x;
    if (r >= n) return;
    float s = 0.f;
    int e1 = rp[r + 1];
    for (int e = rp[r]; e < e1; e++) s += w[lst[e]];
    out[r] = (s != 0.0f) ? 1.0f / s : 0.0f;
}

// Wd_g = W2[0:64] - W2[64:128]; Wd_t = W2[128:192] - W2[192:256]
__global__ void k_wdiff(const float* __restrict__ W2, float* __restrict__ Wd_g,
                        float* __restrict__ Wd_t) {
    int i = blockIdx.x * blockDim.x + threadIdx.x;
    if (i >= DD * DD) return;
    Wd_g[i] = W2[i] - W2[DD * DD + i];
    Wd_t[i] = W2[2 * DD * DD + i] - W2[3 * DD * DD + i];
}

// ---------------- pass A: per-edge contrib = alpha * dist, fp16, edge order ----------------

__global__ __launch_bounds__(256) void k_passA(
        const int* __restrict__ eh, const int* __restrict__ et, int toff,
        const float* __restrict__ feat, const float* __restrict__ intents,
        __half* __restrict__ c_out, int E) {
    __shared__ float Wl[DD * KK];
    for (int idx = threadIdx.x; idx < DD * KK; idx += blockDim.x) Wl[idx] = intents[idx];
    __syncthreads();
    int e = blockIdx.x * blockDim.x + threadIdx.x;
    if (e >= E) return;
    const float4* hp = (const float4*)(feat + (size_t)eh[e] * DD);
    const float4* tp = (const float4*)(feat + (size_t)(et[e] + toff) * DD);
    float logit[KK];
#pragma unroll
    for (int k = 0; k < KK; k++) logit[k] = 0.f;
    float dot = 0.f;
#pragma unroll 4
    for (int l4 = 0; l4 < 16; l4++) {
        float4 h4 = hp[l4], t4 = tp[l4];
        float p0 = h4.x * t4.x, p1 = h4.y * t4.y, p2 = h4.z * t4.z, p3 = h4.w * t4.w;
        dot += p0 + p1 + p2 + p3;
        const float* w = &Wl[l4 * 4 * KK];
#pragma unroll
        for (int k = 0; k < KK; k++)
            logit[k] += p0 * w[k] + p1 * w[KK + k] + p2 * w[2 * KK + k] + p3 * w[3 * KK + k];
    }
    float m = logit[0];
#pragma unroll
    for (int k = 1; k < KK; k++) m = fmaxf(m, logit[k]);
    float ssum = 0.f;
#pragma unroll
    for (int k = 0; k < KK; k++) { float ev = __expf(logit[k] - m); logit[k] = ev; ssum += ev; }
    float scale = 0.5f * (dot + 1.0f) / ssum;   // alpha / softmax denom
    uint4 pk[4];
    unsigned int* u = (unsigned int*)pk;
#pragma unroll
    for (int k2 = 0; k2 < 16; k2++) {
        __half2 hh = __floats2half2_rn(logit[2 * k2] * scale, logit[2 * k2 + 1] * scale);
        u[k2] = *reinterpret_cast<const unsigned int*>(&hh);
    }
    uint4* dst = (uint4*)(c_out + (size_t)e * KK);
#pragma unroll
    for (int q = 0; q < 4; q++) dst[q] = pk[q];
}

// ---------------- pass B+C fused: agg -> recip -> edge weights (CSR order) + inv rowsum ----
__global__ __launch_bounds__(256) void k_passBC(const int* __restrict__ rp,
                                                const int* __restrict__ lst,
                                                const __half* __restrict__ c,
                                                float* __restrict__ w,
                                                float* __restrict__ rsinv, int n) {
    int gid = blockIdx.x * blockDim.x + threadIdx.x;
    int node = gid >> 3, j = gid & 7;
    if (node >= n) return;
    int p0 = rp[node], p1 = rp[node + 1];
    const uint2* cp = (const uint2*)c;   // 8 uint2 per 32-half row
    float4 agg = make_float4(0.f, 0.f, 0.f, 0.f);
    for (int p = p0; p < p1; p++) {
        uint2 v = cp[(size_t)lst[p] * 8 + j];
        float2 fa = __half22float2(*reinterpret_cast<const __half2*>(&v.x));
        float2 fb = __half22float2(*reinterpret_cast<const __half2*>(&v.y));
        agg.x += fa.x; agg.y += fa.y; agg.z += fb.x; agg.w += fb.y;
    }
    float4 rec;
    rec.x = (agg.x != 0.f) ? 1.f / agg.x : 0.f;
    rec.y = (agg.y != 0.f) ? 1.f / agg.y : 0.f;
    rec.z = (agg.z != 0.f) ? 1.f / agg.z : 0.f;
    rec.w = (agg.w != 0.f) ? 1.f / agg.w : 0.f;
    float rs = 0.f;
    for (int p = p0; p < p1; p++) {
        uint2 v = cp[(size_t)lst[p] * 8 + j];
        float2 fa = __half22float2(*reinterpret_cast<const __half2*>(&v.x));
        float2 fb = __half22float2(*reinterpret_cast<const __half2*>(&v.y));
        float dot = fa.x * rec.x + fa.y * rec.y + fb.x * rec.z + fb.y * rec.w;
        dot += __shfl_xor(dot, 1, 64);
        dot += __shfl_xor(dot, 2, 64);
        dot += __shfl_xor(dot, 4, 64);
        float wv = dot * (1.0f / KK);
        if (j == 0) w[p] = wv;
        rs += wv;
    }
    if (j == 0) rsinv[node] = (rs != 0.f) ? 1.f / rs : 0.f;
}

// ---------------- fused UI: g1 + t1 + z-preact, wave per row ----------------
// g1 = sym-norm spmm; t1 = l2norm(rowsum-normed intent spmm);
// z = b2 + g1 @ Wd_g + t1 @ Wd_t. Writes gs, ts, zp rows.
__global__ __launch_bounds__(512) void k_fused_ui(
        const int* __restrict__ rp, const int* __restrict__ lst,
        const int* __restrict__ tails, int tail_off, int row_off,
        const float* __restrict__ w, const float* __restrict__ rsinv,
        const float* __restrict__ dinv, const float* __restrict__ Wd_g,
        const float* __restrict__ Wd_t, const float* __restrict__ b2,
        const float* __restrict__ x, float* __restrict__ gs, float* __restrict__ ts,
        float* __restrict__ zp, int nrows) {
    __shared__ float Wg[DD * DD];
    __shared__ float Wt[DD * DD];
    for (int i = threadIdx.x; i < DD * DD; i += 512) { Wg[i] = Wd_g[i]; Wt[i] = Wd_t[i]; }
    __syncthreads();
    int r = blockIdx.x * 8 + (threadIdx.x >> 6);
    int lane = threadIdx.x & 63;
    if (r >= nrows) return;
    int row_g = r + row_off;
    float accg = 0.f, acct = 0.f;
    float dh = dinv[row_g];
    int e1 = rp[r + 1];
    for (int e = rp[r]; e < e1; e++) {
        int eid = lst[e];
        int col = tails[eid] + tail_off;
        float xv = x[(size_t)col * DD + lane];
        accg += dh * dinv[col] * xv;
        acct += w[e] * xv;
    }
    acct *= rsinv[r];
    float ss = acct * acct;
#pragma unroll
    for (int off = 32; off > 0; off >>= 1) ss += __shfl_xor(ss, off, 64);
    acct *= 1.0f / fmaxf(sqrtf(ss), 1e-12f);
    float zv = b2[lane];
#pragma unroll 8
    for (int l = 0; l < DD; l++) {
        float gl = __shfl(accg, l, 64);
        float tl = __shfl(acct, l, 64);
        zv += gl * Wg[l * DD + lane] + tl * Wt[l * DD + lane];
    }
    size_t oi = (size_t)row_g * DD + lane;
    gs[oi] = accg;
    ts[oi] = acct;
    zp[oi] = zv;
}

// ---------------- fused finalize (UU / II): g2 + t2 + gate + combine ----------------
// g2 = base_w-normed spmm; t2 = l2norm(intent spmm); gfin = gs+g2; tfin = ts+t2;
// z = zp + gfin@W1 + tfin@W3; gate=sigmoid(z); xn = gate*gfin+(1-gate)*tfin;
// xo[row] = xn (xo may alias zp; row-owned); acc[row] += xn.
__global__ __launch_bounds__(512) void k_fused_fin(
        const int* __restrict__ rp, const int* __restrict__ lst,
        const int* __restrict__ tails, int off,
        const float* __restrict__ base_w, const float* __restrict__ base_inv,
        const float* __restrict__ w, const float* __restrict__ rsinv,
        const float* __restrict__ W1, const float* __restrict__ W3,
        const float* __restrict__ x, const float* __restrict__ gs,
        const float* __restrict__ ts, const float* __restrict__ zp,
        float* __restrict__ xo, float* __restrict__ acc, int nrows) {
    __shared__ float Wa[DD * DD];
    __shared__ float Wb[DD * DD];
    for (int i = threadIdx.x; i < DD * DD; i += 512) { Wa[i] = W1[i]; Wb[i] = W3[i]; }
    __syncthreads();
    int r = blockIdx.x * 8 + (threadIdx.x >> 6);
    int lane = threadIdx.x & 63;
    if (r >= nrows) return;
    int row_g = r + off;
    float accg = 0.f, acct = 0.f;
    int e1 = rp[r + 1];
    for (int e = rp[r]; e < e1; e++) {
        int eid = lst[e];
        int col = tails[eid] + off;
        float xv = x[(size_t)col * DD + lane];
        accg += base_w[eid] * xv;
        acct += w[e] * xv;
    }
    accg *= base_inv[r];
    acct *= rsinv[r];
    float ss = acct * acct;
#pragma unroll
    for (int off2 = 32; off2 > 0; off2 >>= 1) ss += __shfl_xor(ss, off2, 64);
    acct *= 1.0f / fmaxf(sqrtf(ss), 1e-12f);
    size_t oi = (size_t)row_g * DD + lane;
    float gfin = gs[oi] + accg;
    float tfin = ts[oi] + acct;
    float zv = zp[oi];
#pragma unroll 8
    for (int l = 0; l < DD; l++) {
        float gl = __shfl(gfin, l, 64);
        float tl = __shfl(tfin, l, 64);
        zv += gl * Wa[l * DD + lane] + tl * Wb[l * DD + lane];
    }
    float gate = 1.0f / (1.0f + __expf(-zv));
    float xn = gate * gfin + (1.0f - gate) * tfin;
    xo[oi] = xn;
    acc[oi] += xn;
}

// ---------------- host launcher ----------------

extern "C" void kernel_launch(void* const* d_in, const int* in_sizes, int n_in,
                              void* d_out, int out_size, void* d_ws, size_t ws_size,
                              hipStream_t stream) {
    const float* user_emb = (const float*)d_in[0];
    const float* item_emb = (const float*)d_in[1];
    const float* intents  = (const float*)d_in[2];
    const float* W2       = (const float*)d_in[3];
    const float* b2       = (const float*)d_in[4];
    const float* uu_w     = (const float*)d_in[5];
    const float* ii_w     = (const float*)d_in[6];
    const int*   ui_u     = (const int*)d_in[7];
    const int*   ui_i     = (const int*)d_in[8];
    const int*   uu_h     = (const int*)d_in[9];
    const int*   uu_t     = (const int*)d_in[10];
    const int*   ii_h     = (const int*)d_in[11];
    const int*   ii_t     = (const int*)d_in[12];
    float* acc = (float*)d_out;

    char* pw = (char*)d_ws;
    auto allocb = [&](size_t nbytes) -> char* {
        char* r = pw;
        pw += (nbytes + 255) & ~(size_t)255;
        return r;
    };
    // ~236 MB total (round-4's proven footprint)
    float* xb   = (float*)allocb((size_t)NN * DD * 4);
    float* gs   = (float*)allocb((size_t)NN * DD * 4);
    float* ts   = (float*)allocb((size_t)NN * DD * 4);
    float* zb   = (float*)allocb((size_t)NN * DD * 4);
    __half* c   = (__half*)allocb((size_t)EUI * KK * 2);   // 64 MB, reused UI/UU/II
    float* w    = (float*)allocb((size_t)EUI * 4);
    float* rs   = (float*)allocb((size_t)NU * 4);
    float* dinv = (float*)allocb((size_t)NN * 4);
    float* iuu  = (float*)allocb((size_t)NU * 4);
    float* iii  = (float*)allocb((size_t)NI * 4);
    float* Wd_g = (float*)allocb((size_t)DD * DD * 4);
    float* Wd_t = (float*)allocb((size_t)DD * DD * 4);
    int* rp_u   = (int*)allocb(((size_t)NU + 1) * 4);
    int* rp_i   = (int*)allocb(((size_t)NI + 1) * 4);
    int* rp_uu  = (int*)allocb(((size_t)NU + 1) * 4);
    int* rp_ii  = (int*)allocb(((size_t)NI + 1) * 4);
    int* lst_u  = (int*)allocb((size_t)EUI * 4);
    int* lst_i  = (int*)allocb((size_t)EUI * 4);
    int* lst_uu = (int*)allocb((size_t)EUU * 4);
    int* lst_ii = (int*)allocb((size_t)EII * 4);
    int* cur    = (int*)c;   // alias: CSR build finishes before c is used

    const int B = 256;

    auto build_csr = [&](const int* h, int E, int n, int* rp, int* lst) {
        hipMemsetAsync(cur, 0, (size_t)n * 4, stream);
        k_count<<<cdiv(E, B), B, 0, stream>>>(h, cur, E);
        k_scan<<<1, 1024, 0, stream>>>(cur, rp, n);
        hipMemsetAsync(cur, 0, (size_t)n * 4, stream);
        k_scatter<<<cdiv(E, B), B, 0, stream>>>(h, rp, cur, lst, E);
    };

    build_csr(ui_u, EUI, NU, rp_u, lst_u);
    build_csr(ui_i, EUI, NI, rp_i, lst_i);
    build_csr(uu_h, EUU, NU, rp_uu, lst_uu);
    build_csr(ii_h, EII, NI, rp_ii, lst_ii);
    k_dinv<<<cdiv(NN, B), B, 0, stream>>>(rp_u, rp_i, dinv);
    k_rowsum_inv<<<cdiv(NU, B), B, 0, stream>>>(rp_uu, lst_uu, uu_w, iuu, NU);
    k_rowsum_inv<<<cdiv(NI, B), B, 0, stream>>>(rp_ii, lst_ii, ii_w, iii, NI);
    k_wdiff<<<cdiv(DD * DD, B), B, 0, stream>>>(W2, Wd_g, Wd_t);

    hipMemcpyAsync(xb, user_emb, (size_t)NU * DD * 4, hipMemcpyDeviceToDevice, stream);
    hipMemcpyAsync(xb + (size_t)NU * DD, item_emb, (size_t)NI * DD * 4, hipMemcpyDeviceToDevice, stream);
    hipMemcpyAsync(acc, xb, (size_t)NN * DD * 4, hipMemcpyDeviceToDevice, stream);

    for (int layer = 0; layer < 2; ++layer) {
        const float* xin = (layer == 0) ? xb : zb;
        float* xo = (layer == 0) ? zb : xb;   // preact + next-x buffer

        // ---- UI: passA -> (passBC -> fused g1+t1+zpre) per side ----
        k_passA<<<cdiv(EUI, B), B, 0, stream>>>(ui_u, ui_i, NU, xin, intents, c, EUI);
        k_passBC<<<cdiv((long)NU * 8, B), B, 0, stream>>>(rp_u, lst_u, c, w, rs, NU);
        k_fused_ui<<<cdiv(NU, 8), 512, 0, stream>>>(rp_u, lst_u, ui_i, NU, 0, w, rs,
                                                    dinv, Wd_g, Wd_t, b2, xin, gs, ts, xo, NU);
        k_passBC<<<cdiv((long)NI * 8, B), B, 0, stream>>>(rp_i, lst_i, c, w, rs, NI);
        k_fused_ui<<<cdiv(NI, 8), 512, 0, stream>>>(rp_i, lst_i, ui_u, 0, NU, w, rs,
                                                    dinv, Wd_g, Wd_t, b2, xin, gs, ts, xo, NI);

        // ---- UU: passA -> passBC -> finalize user rows ----
        k_passA<<<cdiv(EUU, B), B, 0, stream>>>(uu_h, uu_t, 0, xin, intents, c, EUU);
        k_passBC<<<cdiv((long)NU * 8, B), B, 0, stream>>>(rp_uu, lst_uu, c, w, rs, NU);
        k_fused_fin<<<cdiv(NU, 8), 512, 0, stream>>>(rp_uu, lst_uu, uu_t, 0, uu_w, iuu,
                                                     w, rs, W2 + DD * DD, W2 + 3 * DD * DD,
                                                     xin, gs, ts, xo, xo, acc, NU);

        // ---- II: passA -> passBC -> finalize item rows ----
        k_passA<<<cdiv(EII, B), B, 0, stream>>>(ii_h, ii_t, 0, xin + (size_t)NU * DD, intents, c, EII);
        k_passBC<<<cdiv((long)NI * 8, B), B, 0, stream>>>(rp_ii, lst_ii, c, w, rs, NI);
        k_fused_fin<<<cdiv(NI, 8), 512, 0, stream>>>(rp_ii, lst_ii, ii_t, NU, ii_w, iii,
                                                     w, rs, W2 + DD * DD, W2 + 3 * DD * DD,
                                                     xin, gs, ts, xo, xo, acc, NI);
    }
}